// Round 1
// baseline (256.934 us; speedup 1.0000x reference)
//
#include <hip/hip_runtime.h>

#define N_B   2048
#define C_IN  64
#define C_SG  32
#define F_SIG 1056
#define F_PAD 1088
#define K_CLS 100
#define K_PAD 128

// ---------- transpose conv_w[oc][cin][3][3] -> wT[(cin*9+tap)*32 + oc] ----------
__global__ void k_wt(const float* __restrict__ cw, float* __restrict__ wT) {
    int e = blockIdx.x * 256 + threadIdx.x;
    if (e < 32 * 576) {
        int oc = e / 576, r = e - oc * 576;
        wT[r * 32 + oc] = cw[e];
    }
}

// ---------- transpose lin_w (1056x1056) -> lwT[i][o] ----------
__global__ void k_lwt(const float* __restrict__ lw, float* __restrict__ lwT) {
    __shared__ float tile[32][33];
    int bx = blockIdx.x * 32, by = blockIdx.y * 32;
    int tx = threadIdx.x & 31, ty = threadIdx.x >> 5;
    for (int yy = ty; yy < 32; yy += 8)
        tile[yy][tx] = lw[(size_t)(by + yy) * F_SIG + bx + tx];
    __syncthreads();
    for (int yy = ty; yy < 32; yy += 8)
        lwT[(size_t)(bx + yy) * F_SIG + by + tx] = tile[tx][yy];
}

// ---------- conv(64->32,3x3,pad1) + Zhang signature depth-2, one image per block ----------
__launch_bounds__(256)
__global__ void k_convsig(const float* __restrict__ x, const float* __restrict__ wT,
                          float* __restrict__ sig) {
    __shared__ float xs[6400];   // [cin][10*10] zero-padded
    __shared__ float ys[2048];   // [oc][64]
    __shared__ float Ds[1568];   // [c][49]
    __shared__ float Ps[1568];   // [c][49]
    const int tid = threadIdx.x;
    const int b = blockIdx.x;

    for (int e = tid; e < 6400; e += 256) xs[e] = 0.f;
    __syncthreads();
    const float* xb = x + (size_t)b * 4096;
    for (int e = tid; e < 4096; e += 256) {
        int cin = e >> 6, p = e & 63;
        int ih = p >> 3, iw = p & 7;
        xs[cin * 100 + (ih + 1) * 10 + (iw + 1)] = xb[e];
    }
    __syncthreads();

    const int og  = __builtin_amdgcn_readfirstlane(tid >> 6);  // wave id: 8 oc per wave
    const int pos = tid & 63;
    const int oh = pos >> 3, ow = pos & 7;
    float acc[8];
#pragma unroll
    for (int o = 0; o < 8; ++o) acc[o] = 0.f;
    const float* wp = wT + og * 8;
    const int xa = oh * 10 + ow;
    for (int cin = 0; cin < 64; ++cin) {
        const float* xc = xs + cin * 100 + xa;
        const float* wc = wp + cin * 288;
#pragma unroll
        for (int t9 = 0; t9 < 9; ++t9) {
            float a = xc[(t9 / 3) * 10 + (t9 % 3)];
            const float* w8 = wc + t9 * 32;
#pragma unroll
            for (int o = 0; o < 8; ++o) acc[o] = fmaf(a, w8[o], acc[o]);
        }
    }
#pragma unroll
    for (int o = 0; o < 8; ++o) ys[(og * 8 + o) * 64 + pos] = acc[o];
    __syncthreads();

    // double increments D (7x7 per channel)
    for (int e = tid; e < 1568; e += 256) {
        int c = e / 49, q = e - c * 49;
        int i = q / 7, j = q - i * 7;
        const float* yc = ys + c * 64;
        Ds[e] = yc[(i + 1) * 8 + (j + 1)] - yc[(i + 1) * 8 + j]
              - yc[i * 8 + (j + 1)] + yc[i * 8 + j];
    }
    __syncthreads();

    // strict 2D prefix P, plus level-1 sums; 32 threads, one channel each
    if (tid < 32) {
        const int c = tid;
        const float* Dc = Ds + c * 49;
        float* Pc = Ps + c * 49;
        float Iprev[7];
#pragma unroll
        for (int j = 0; j < 7; ++j) Iprev[j] = 0.f;
#pragma unroll
        for (int i = 0; i < 7; ++i) {
            float rs = 0.f, diag = 0.f;
#pragma unroll
            for (int j = 0; j < 7; ++j) {
                float Pv = (i == 0 || j == 0) ? 0.f : diag;
                Pc[i * 7 + j] = Pv;
                rs += Dc[i * 7 + j];
                float old = Iprev[j];
                Iprev[j] = rs + old;   // inclusive 2D prefix
                diag = old;
            }
        }
        sig[(size_t)b * F_PAD + c] = Iprev[6];         // L1 = total sum of D
        sig[(size_t)b * F_PAD + F_SIG + c] = 0.f;      // zero the row padding
    }
    __syncthreads();

    // level-2: L2[c1,c2] = sum_q P[c1][q]*D[c2][q]
    for (int e = tid; e < 1024; e += 256) {
        int c1 = e >> 5, c2 = e & 31;
        const float* Pp = Ps + c1 * 49;
        const float* Dp = Ds + c2 * 49;
        float d = 0.f;
#pragma unroll
        for (int q = 0; q < 49; ++q) d = fmaf(Pp[q], Dp[q], d);
        sig[(size_t)b * F_PAD + 32 + e] = d;
    }
}

// ---------- per-feature sum / sumsq over batch ----------
__global__ void k_stats(const float* __restrict__ sig, float* __restrict__ sums,
                        float* __restrict__ sqs) {
    int f = blockIdx.x * 256 + threadIdx.x;
    if (f >= F_SIG) return;
    int r0 = blockIdx.y * 32;
    float s = 0.f, q = 0.f;
    for (int r = r0; r < r0 + 32; ++r) {
        float v = sig[(size_t)r * F_PAD + f];
        s += v;
        q = fmaf(v, v, q);
    }
    atomicAdd(&sums[f], s);
    atomicAdd(&sqs[f], q);
}

// ---------- BN fold: A = gamma*rsqrt(var+eps), Bv = beta - mean*A ----------
__global__ void k_ab(const float* __restrict__ sums, const float* __restrict__ sqs,
                     const float* __restrict__ gamma, const float* __restrict__ beta,
                     float* __restrict__ Av, float* __restrict__ Bv) {
    int i = blockIdx.x * 256 + threadIdx.x;
    if (i >= F_PAD) return;
    float a = 0.f, bb = 0.f;
    if (i < F_SIG) {
        float m   = sums[i] * (1.f / 2048.f);
        float var = sqs[i] * (1.f / 2048.f) - m * m;
        a  = gamma[i] / sqrtf(var + 1e-5f);
        bb = beta[i] - m * a;
    }
    Av[i] = a;
    Bv[i] = bb;
}

// ---------- t[o] = lin_b[o] + sum_i Bv[i]*lin_w[o,i] ----------
__global__ void k_t(const float* __restrict__ lw, const float* __restrict__ Bv,
                    const float* __restrict__ lb, float* __restrict__ tvec) {
    int o = blockIdx.x, tid = threadIdx.x;
    const float* lr = lw + (size_t)o * F_SIG;
    float s = 0.f;
    for (int i = tid; i < F_SIG; i += 256) s = fmaf(Bv[i], lr[i], s);
#pragma unroll
    for (int d = 32; d; d >>= 1) s += __shfl_xor(s, d);
    __shared__ float red[4];
    if ((tid & 63) == 0) red[tid >> 6] = s;
    __syncthreads();
    if (tid == 0) tvec[o] = lb[o] + red[0] + red[1] + red[2] + red[3];
}

// ---------- Wf[k,i] = A[i] * sum_o fc_w[k,o]*lwT[i,o]  (padded to 128x1088) ----------
__launch_bounds__(256)
__global__ void k_wf(const float* __restrict__ fcw, const float* __restrict__ lwT,
                     const float* __restrict__ Av, float* __restrict__ Wf) {
    int i = blockIdx.x * 32 + (threadIdx.x & 31);
    int k = blockIdx.y * 8 + (threadIdx.x >> 5);
    float r = 0.f;
    if (k < K_CLS && i < F_SIG) {
        const float* fr = fcw + (size_t)k * F_SIG;
        const float* lr = lwT + (size_t)i * F_SIG;
        float a0 = 0.f, a1 = 0.f, a2 = 0.f, a3 = 0.f;
        for (int o = 0; o < F_SIG; o += 4) {
            float4 fv = *reinterpret_cast<const float4*>(fr + o);
            float4 lv = *reinterpret_cast<const float4*>(lr + o);
            a0 = fmaf(fv.x, lv.x, a0);
            a1 = fmaf(fv.y, lv.y, a1);
            a2 = fmaf(fv.z, lv.z, a2);
            a3 = fmaf(fv.w, lv.w, a3);
        }
        r = (a0 + a1 + a2 + a3) * Av[i];
    }
    Wf[(size_t)k * F_PAD + i] = r;
}

// ---------- bf[k] = fc_b[k] + sum_o fc_w[k,o]*t[o] ----------
__global__ void k_bf(const float* __restrict__ fcw, const float* __restrict__ tvec,
                     const float* __restrict__ fcb, float* __restrict__ bf) {
    int k = blockIdx.x, tid = threadIdx.x;
    float s = 0.f;
    if (k < K_CLS) {
        const float* fr = fcw + (size_t)k * F_SIG;
        for (int o = tid; o < F_SIG; o += 256) s = fmaf(fr[o], tvec[o], s);
    }
#pragma unroll
    for (int d = 32; d; d >>= 1) s += __shfl_xor(s, d);
    __shared__ float red[4];
    if ((tid & 63) == 0) red[tid >> 6] = s;
    __syncthreads();
    if (tid == 0) {
        float tot = red[0] + red[1] + red[2] + red[3];
        bf[k] = (k < K_CLS) ? (tot + fcb[k]) : 0.f;
    }
}

// ---------- out[n,k] = sum_i sig[n,i]*Wf[k,i] + bf[k]; lane-split K, wave per row ----------
__launch_bounds__(256)
__global__ void k_out(const float* __restrict__ sig, const float* __restrict__ Wf,
                      const float* __restrict__ bf, float* __restrict__ out) {
    const int w = threadIdx.x >> 6, l = threadIdx.x & 63;
    const int r = blockIdx.x * 4 + w;
    const float* sp = sig + (size_t)r * F_PAD + l * 17;
    float s[17];
#pragma unroll
    for (int j = 0; j < 17; ++j) s[j] = sp[j];
    const float* wbase = Wf + l * 17;
    for (int k = 0; k < K_CLS; ++k) {
        const float* wk = wbase + (size_t)k * F_PAD;
        float a = 0.f;
#pragma unroll
        for (int j = 0; j < 17; ++j) a = fmaf(s[j], wk[j], a);
#pragma unroll
        for (int d = 32; d; d >>= 1) a += __shfl_xor(a, d);
        if (l == 0) out[r * K_CLS + k] = a + bf[k];
    }
}

extern "C" void kernel_launch(void* const* d_in, const int* in_sizes, int n_in,
                              void* d_out, int out_size, void* d_ws, size_t ws_size,
                              hipStream_t stream) {
    (void)in_sizes; (void)n_in; (void)out_size; (void)ws_size;
    const float* feats = (const float*)d_in[0];
    const float* convw = (const float*)d_in[1];
    const float* gamma = (const float*)d_in[2];
    const float* beta  = (const float*)d_in[3];
    const float* linw  = (const float*)d_in[4];
    const float* linb  = (const float*)d_in[5];
    const float* fcw   = (const float*)d_in[6];
    const float* fcb   = (const float*)d_in[7];
    float* out = (float*)d_out;

    float* ws   = (float*)d_ws;
    float* sig  = ws;                                   // 2048*1088
    float* sums = sig + (size_t)N_B * F_PAD;            // 1088
    float* sqs  = sums + F_PAD;                         // 1088
    float* Av   = sqs + F_PAD;                          // 1088
    float* Bv   = Av + F_PAD;                           // 1088
    float* lwT  = Bv + F_PAD;                           // 1056*1056
    float* tvec = lwT + (size_t)F_SIG * F_SIG;          // 1056
    float* Wf   = tvec + F_SIG;                         // 128*1088
    float* bfv  = Wf + (size_t)K_PAD * F_PAD;           // 128
    float* wT   = bfv + K_PAD;                          // 576*32

    k_wt<<<72, 256, 0, stream>>>(convw, wT);
    k_lwt<<<dim3(33, 33), 256, 0, stream>>>(linw, lwT);
    hipMemsetAsync(sums, 0, 2 * F_PAD * sizeof(float), stream);
    k_convsig<<<N_B, 256, 0, stream>>>(feats, wT, sig);
    k_stats<<<dim3(5, 64), 256, 0, stream>>>(sig, sums, sqs);
    k_ab<<<5, 256, 0, stream>>>(sums, sqs, gamma, beta, Av, Bv);
    k_t<<<F_SIG, 256, 0, stream>>>(linw, Bv, linb, tvec);
    k_wf<<<dim3(34, 16), 256, 0, stream>>>(fcw, lwT, Av, Wf);
    k_bf<<<K_PAD, 256, 0, stream>>>(fcw, tvec, fcb, bfv);
    k_out<<<512, 256, 0, stream>>>(sig, Wf, bfv, out);
}

// Round 2
// 243.714 us; speedup vs baseline: 1.0542x; 1.0542x over previous
//
#include <hip/hip_runtime.h>

#define N_B   2048
#define C_IN  64
#define C_SG  32
#define F_SIG 1056
#define F_PAD 1088
#define K_CLS 100
#define K_PAD 128

#define XS_STRIDE 11          // 10 rows x 11 floats per cin (pad for banks)
#define XS_PER_C  110
#define DROW      52          // 49 real + 3 pad, 16B-aligned rows

// ---------- transpose conv_w[oc][cin][3][3] -> wT[(cin*9+tap)*32 + oc] ----------
__global__ void k_wt(const float* __restrict__ cw, float* __restrict__ wT) {
    int e = blockIdx.x * 256 + threadIdx.x;
    if (e < 32 * 576) {
        int oc = e / 576, r = e - oc * 576;
        wT[r * 32 + oc] = cw[e];
    }
}

// ---------- conv(64->32,3x3,pad1) + Zhang signature depth-2, one image per block ----------
__launch_bounds__(256, 4)
__global__ void k_convsig(const float* __restrict__ x, const float* __restrict__ wT,
                          float* __restrict__ sig) {
    __shared__ __align__(16) float buf[7040 + 2048];   // xs[64*110] | ys[32*64]
    float* xs = buf;                  // phase A
    float* ys = buf + 7040;
    float* Ds = buf;                  // phase B aliases (xs dead)
    float* Ps = buf + 1664;
    float* Cs = buf + 3328;
    const int tid = threadIdx.x;
    const int b = blockIdx.x;

    // zero-fill padded activation tile, then scatter the 8x8 interior (disjoint cells)
    for (int e = tid; e < 7040; e += 256) xs[e] = 0.f;
    const float4* xb4 = reinterpret_cast<const float4*>(x + (size_t)b * 4096);
    for (int e = tid; e < 1024; e += 256) {
        float4 v = xb4[e];
        int cin = e >> 4, p = (e & 15) * 4;
        int ih = p >> 3, iw = p & 7;                       // iw in {0,4}
        float* dst = xs + cin * XS_PER_C + (ih + 1) * XS_STRIDE + (iw + 1);
        dst[0] = v.x; dst[1] = v.y; dst[2] = v.z; dst[3] = v.w;
    }
    __syncthreads();

    // conv: wave og computes 8 output channels for all 64 positions
    const int og  = __builtin_amdgcn_readfirstlane(tid >> 6);
    const int pos = tid & 63;
    const int oh = pos >> 3, ow = pos & 7;
    float acc[8];
#pragma unroll
    for (int o = 0; o < 8; ++o) acc[o] = 0.f;
    const float* wp = wT + og * 8;
    const int xa = oh * XS_STRIDE + ow;
    for (int cin = 0; cin < 64; ++cin) {
        const float* xc = xs + cin * XS_PER_C + xa;
        const float* wc = wp + cin * 288;
#pragma unroll
        for (int t9 = 0; t9 < 9; ++t9) {
            float a = xc[(t9 / 3) * XS_STRIDE + (t9 % 3)];
            const float* w8 = wc + t9 * 32;
#pragma unroll
            for (int o = 0; o < 8; ++o) acc[o] = fmaf(a, w8[o], acc[o]);
        }
    }
#pragma unroll
    for (int o = 0; o < 8; ++o) ys[(og * 8 + o) * 64 + pos] = acc[o];
    __syncthreads();

    // double increments D[c][52] (49 real, pad zero)
    for (int e = tid; e < 32 * DROW; e += 256) {
        int c = e / DROW, q = e - c * DROW;
        float v = 0.f;
        if (q < 49) {
            int i = q / 7, j = q - i * 7;
            const float* yc = ys + c * 64;
            v = yc[(i + 1) * 8 + (j + 1)] - yc[(i + 1) * 8 + j]
              - yc[i * 8 + (j + 1)] + yc[i * 8 + j];
        }
        Ds[e] = v;
    }
    __syncthreads();

    // pass 1: Cs[c][i,j] = sum_{ii<i} D[c][ii,j]  (strict column prefix)
    for (int e = tid; e < 32 * DROW; e += 256) {
        int c = e / DROW, q = e - c * DROW;
        float v = 0.f;
        if (q < 49) {
            int i = q / 7, j = q - i * 7;
            const float* Dc = Ds + c * DROW;
            for (int ii = 0; ii < i; ++ii) v += Dc[ii * 7 + j];
        }
        Cs[e] = v;
    }
    __syncthreads();

    // pass 2: Ps[c][i,j] = sum_{jj<j} Cs[c][i,jj]  (strict 2D prefix)
    for (int e = tid; e < 32 * DROW; e += 256) {
        int c = e / DROW, q = e - c * DROW;
        float v = 0.f;
        if (q < 49) {
            int i = q / 7, j = q - i * 7;
            const float* Cc = Cs + c * DROW;
            for (int jj = 0; jj < j; ++jj) v += Cc[i * 7 + jj];
        }
        Ps[e] = v;
    }
    __syncthreads();

    // level-2: 2x2 register-blocked, vectorized LDS reads.
    {
        const int bc1 = tid >> 4, bc2 = tid & 15;       // c1 in {bc1,bc1+16}, c2 likewise
        const float* P0 = Ps + bc1 * DROW;
        const float* P1 = Ps + (bc1 + 16) * DROW;
        const float* D0 = Ds + bc2 * DROW;
        const float* D1 = Ds + (bc2 + 16) * DROW;
        float a00 = 0.f, a01 = 0.f, a10 = 0.f, a11 = 0.f;
#pragma unroll
        for (int qb = 0; qb < DROW; qb += 4) {
            float4 p0 = *reinterpret_cast<const float4*>(P0 + qb);
            float4 p1 = *reinterpret_cast<const float4*>(P1 + qb);
            float4 d0 = *reinterpret_cast<const float4*>(D0 + qb);
            float4 d1 = *reinterpret_cast<const float4*>(D1 + qb);
            a00 += p0.x*d0.x + p0.y*d0.y + p0.z*d0.z + p0.w*d0.w;
            a01 += p0.x*d1.x + p0.y*d1.y + p0.z*d1.z + p0.w*d1.w;
            a10 += p1.x*d0.x + p1.y*d0.y + p1.z*d0.z + p1.w*d0.w;
            a11 += p1.x*d1.x + p1.y*d1.y + p1.z*d1.z + p1.w*d1.w;
        }
        float* so = sig + (size_t)b * F_PAD + 32;
        so[bc1 * 32 + bc2]               = a00;
        so[bc1 * 32 + (bc2 + 16)]        = a01;
        so[(bc1 + 16) * 32 + bc2]        = a10;
        so[(bc1 + 16) * 32 + (bc2 + 16)] = a11;
    }

    // level-1 sums (rows padded with zeros -> sum 52 via float4) + zero sig pad
    if (tid < 32) {
        const float4* Dr = reinterpret_cast<const float4*>(Ds + tid * DROW);
        float4 s4 = {0.f, 0.f, 0.f, 0.f};
#pragma unroll
        for (int j = 0; j < 13; ++j) {
            float4 v = Dr[j];
            s4.x += v.x; s4.y += v.y; s4.z += v.z; s4.w += v.w;
        }
        sig[(size_t)b * F_PAD + tid] = s4.x + s4.y + s4.z + s4.w;
    } else if (tid < 64) {
        sig[(size_t)b * F_PAD + F_SIG + (tid - 32)] = 0.f;
    }
}

// ---------- per-feature sum / sumsq over batch ----------
__global__ void k_stats(const float* __restrict__ sig, float* __restrict__ sums,
                        float* __restrict__ sqs) {
    int f = blockIdx.x * 256 + threadIdx.x;
    if (f >= F_SIG) return;
    int r0 = blockIdx.y * 32;
    float s = 0.f, q = 0.f;
    for (int r = r0; r < r0 + 32; ++r) {
        float v = sig[(size_t)r * F_PAD + f];
        s += v;
        q = fmaf(v, v, q);
    }
    atomicAdd(&sums[f], s);
    atomicAdd(&sqs[f], q);
}

// ---------- BN fold: A = gamma*rsqrt(var+eps), Bv = beta - mean*A ----------
__global__ void k_ab(const float* __restrict__ sums, const float* __restrict__ sqs,
                     const float* __restrict__ gamma, const float* __restrict__ beta,
                     float* __restrict__ Av, float* __restrict__ Bv) {
    int i = blockIdx.x * 256 + threadIdx.x;
    if (i >= F_PAD) return;
    float a = 0.f, bb = 0.f;
    if (i < F_SIG) {
        float m   = sums[i] * (1.f / 2048.f);
        float var = sqs[i] * (1.f / 2048.f) - m * m;
        a  = gamma[i] / sqrtf(var + 1e-5f);
        bb = beta[i] - m * a;
    }
    Av[i] = a;
    Bv[i] = bb;
}

// ---------- t[o] = lin_b[o] + sum_i Bv[i]*lin_w[o,i] ----------
__global__ void k_t(const float* __restrict__ lw, const float* __restrict__ Bv,
                    const float* __restrict__ lb, float* __restrict__ tvec) {
    int o = blockIdx.x, tid = threadIdx.x;
    const float* lr = lw + (size_t)o * F_SIG;
    float s = 0.f;
    for (int i = tid; i < F_SIG; i += 256) s = fmaf(Bv[i], lr[i], s);
#pragma unroll
    for (int d = 32; d; d >>= 1) s += __shfl_xor(s, d);
    __shared__ float red[4];
    if ((tid & 63) == 0) red[tid >> 6] = s;
    __syncthreads();
    if (tid == 0) tvec[o] = lb[o] + red[0] + red[1] + red[2] + red[3];
}

// ---------- Wf[k,i] = A[i] * sum_o fcw[k,o]*lin_w[o,i]; lanes along i (coalesced) ----------
__launch_bounds__(256)
__global__ void k_wf(const float* __restrict__ fcw, const float* __restrict__ lw,
                     const float* __restrict__ Av, float* __restrict__ Wf) {
    const int k  = __builtin_amdgcn_readfirstlane(blockIdx.y * 4 + (threadIdx.x >> 6));
    const int ib = blockIdx.x * 256 + (threadIdx.x & 63) * 4;
    float r0 = 0.f, r1 = 0.f, r2 = 0.f, r3 = 0.f;
    if (ib < F_SIG) {
        const float* fr = fcw + (size_t)k * F_SIG;
        for (int o = 0; o < F_SIG; ++o) {
            float s = fr[o];
            float4 v = *reinterpret_cast<const float4*>(lw + (size_t)o * F_SIG + ib);
            r0 = fmaf(s, v.x, r0);
            r1 = fmaf(s, v.y, r1);
            r2 = fmaf(s, v.z, r2);
            r3 = fmaf(s, v.w, r3);
        }
        float4 av = *reinterpret_cast<const float4*>(Av + ib);
        r0 *= av.x; r1 *= av.y; r2 *= av.z; r3 *= av.w;
    }
    if (ib < F_PAD) {
        float4 outv = (ib < F_SIG) ? make_float4(r0, r1, r2, r3)
                                   : make_float4(0.f, 0.f, 0.f, 0.f);
        *reinterpret_cast<float4*>(Wf + (size_t)k * F_PAD + ib) = outv;
    }
}

// ---------- bf[k] = fc_b[k] + sum_o fc_w[k,o]*t[o] ----------
__global__ void k_bf(const float* __restrict__ fcw, const float* __restrict__ tvec,
                     const float* __restrict__ fcb, float* __restrict__ bf) {
    int k = blockIdx.x, tid = threadIdx.x;
    float s = 0.f;
    if (k < K_CLS) {
        const float* fr = fcw + (size_t)k * F_SIG;
        for (int o = tid; o < F_SIG; o += 256) s = fmaf(fr[o], tvec[o], s);
    }
#pragma unroll
    for (int d = 32; d; d >>= 1) s += __shfl_xor(s, d);
    __shared__ float red[4];
    if ((tid & 63) == 0) red[tid >> 6] = s;
    __syncthreads();
    if (tid == 0) {
        float tot = red[0] + red[1] + red[2] + red[3];
        bf[k] = (k < K_CLS) ? (tot + fcb[k]) : 0.f;
    }
}

// ---------- out[n,k] = sum_i sig[n,i]*Wf[k,i] + bf[k]; lane-split K, wave per row ----------
__launch_bounds__(256)
__global__ void k_out(const float* __restrict__ sig, const float* __restrict__ Wf,
                      const float* __restrict__ bf, float* __restrict__ out) {
    const int w = threadIdx.x >> 6, l = threadIdx.x & 63;
    const int r = blockIdx.x * 4 + w;
    const float* sp = sig + (size_t)r * F_PAD + l * 17;
    float s[17];
#pragma unroll
    for (int j = 0; j < 17; ++j) s[j] = sp[j];
    const float* wbase = Wf + l * 17;
    for (int k = 0; k < K_CLS; ++k) {
        const float* wk = wbase + (size_t)k * F_PAD;
        float a = 0.f;
#pragma unroll
        for (int j = 0; j < 17; ++j) a = fmaf(s[j], wk[j], a);
#pragma unroll
        for (int d = 32; d; d >>= 1) a += __shfl_xor(a, d);
        if (l == 0) out[r * K_CLS + k] = a + bf[k];
    }
}

extern "C" void kernel_launch(void* const* d_in, const int* in_sizes, int n_in,
                              void* d_out, int out_size, void* d_ws, size_t ws_size,
                              hipStream_t stream) {
    (void)in_sizes; (void)n_in; (void)out_size; (void)ws_size;
    const float* feats = (const float*)d_in[0];
    const float* convw = (const float*)d_in[1];
    const float* gamma = (const float*)d_in[2];
    const float* beta  = (const float*)d_in[3];
    const float* linw  = (const float*)d_in[4];
    const float* linb  = (const float*)d_in[5];
    const float* fcw   = (const float*)d_in[6];
    const float* fcb   = (const float*)d_in[7];
    float* out = (float*)d_out;

    float* ws   = (float*)d_ws;
    float* sig  = ws;                                   // 2048*1088
    float* sums = sig + (size_t)N_B * F_PAD;            // 1088
    float* sqs  = sums + F_PAD;                         // 1088
    float* Av   = sqs + F_PAD;                          // 1088
    float* Bv   = Av + F_PAD;                           // 1088
    float* tvec = Bv + F_PAD;                           // 1056
    float* Wf   = tvec + F_SIG;                         // 128*1088
    float* bfv  = Wf + (size_t)K_PAD * F_PAD;           // 128
    float* wT   = bfv + K_PAD;                          // 576*32

    k_wt<<<72, 256, 0, stream>>>(convw, wT);
    hipMemsetAsync(sums, 0, 2 * F_PAD * sizeof(float), stream);
    k_convsig<<<N_B, 256, 0, stream>>>(feats, wT, sig);
    k_stats<<<dim3(5, 64), 256, 0, stream>>>(sig, sums, sqs);
    k_ab<<<5, 256, 0, stream>>>(sums, sqs, gamma, beta, Av, Bv);
    k_t<<<F_SIG, 256, 0, stream>>>(linw, Bv, linb, tvec);
    k_wf<<<dim3(5, 25), 256, 0, stream>>>(fcw, linw, Av, Wf);
    k_bf<<<K_PAD, 256, 0, stream>>>(fcw, tvec, fcb, bfv);
    k_out<<<512, 256, 0, stream>>>(sig, Wf, bfv, out);
}

// Round 3
// 189.264 us; speedup vs baseline: 1.3575x; 1.2877x over previous
//
#include <hip/hip_runtime.h>

#define N_B   2048
#define C_IN  64
#define C_SG  32
#define F_SIG 1056
#define F_PAD 1088
#define K_CLS 100
#define K_PAD 128

#define XS_STRIDE 12          // 10 rows x 12 floats per cin: row starts mod 32 tile banks 2x
#define XS_PER_C  120
#define DROW      52          // 49 real + 3 pad, 16B-aligned rows
#define OSPLIT    8           // split-K chunks in k_wf
#define OCHUNK    132         // 1056/8

// ---------- transpose conv_w[oc][cin][3][3] -> wT[(cin*9+tap)*32 + oc] ----------
__global__ void k_wt(const float* __restrict__ cw, float* __restrict__ wT) {
    int e = blockIdx.x * 256 + threadIdx.x;
    if (e < 32 * 576) {
        int oc = e / 576, r = e - oc * 576;
        wT[r * 32 + oc] = cw[e];
    }
}

// ---------- conv(64->32,3x3,pad1) + Zhang signature depth-2, one image per block ----------
__launch_bounds__(256, 4)
__global__ void k_convsig(const float* __restrict__ x, const float* __restrict__ wT,
                          float* __restrict__ sig) {
    __shared__ __align__(16) float buf[7680 + 2048];   // xs[64*120] | ys[32*64]
    float* xs = buf;                  // phase A
    float* ys = buf + 7680;
    float* Ds = buf;                  // phase B aliases (xs dead)
    float* Ps = buf + 1664;
    float* Cs = buf + 3328;
    const int tid = threadIdx.x;
    const int b = blockIdx.x;

    for (int e = tid; e < 7680; e += 256) xs[e] = 0.f;
    const float4* xb4 = reinterpret_cast<const float4*>(x + (size_t)b * 4096);
    for (int e = tid; e < 1024; e += 256) {
        float4 v = xb4[e];
        int cin = e >> 4, p = (e & 15) * 4;
        int ih = p >> 3, iw = p & 7;                       // iw in {0,4}
        float* dst = xs + cin * XS_PER_C + (ih + 1) * XS_STRIDE + (iw + 1);
        dst[0] = v.x; dst[1] = v.y; dst[2] = v.z; dst[3] = v.w;
    }
    __syncthreads();

    // conv: wave og computes 8 output channels for all 64 positions
    const int og  = __builtin_amdgcn_readfirstlane(tid >> 6);
    const int pos = tid & 63;
    const int oh = pos >> 3, ow = pos & 7;
    float acc[8];
#pragma unroll
    for (int o = 0; o < 8; ++o) acc[o] = 0.f;
    const float* wp = wT + og * 8;
    const int xa = oh * XS_STRIDE + ow;
    for (int cin = 0; cin < 64; ++cin) {
        const float* xc = xs + cin * XS_PER_C + xa;
        const float* wc = wp + cin * 288;
#pragma unroll
        for (int t9 = 0; t9 < 9; ++t9) {
            float a = xc[(t9 / 3) * XS_STRIDE + (t9 % 3)];
            const float* w8 = wc + t9 * 32;
#pragma unroll
            for (int o = 0; o < 8; ++o) acc[o] = fmaf(a, w8[o], acc[o]);
        }
    }
#pragma unroll
    for (int o = 0; o < 8; ++o) ys[(og * 8 + o) * 64 + pos] = acc[o];
    __syncthreads();

    // double increments D[c][52] (49 real, pad zero)
    for (int e = tid; e < 32 * DROW; e += 256) {
        int c = e / DROW, q = e - c * DROW;
        float v = 0.f;
        if (q < 49) {
            int i = q / 7, j = q - i * 7;
            const float* yc = ys + c * 64;
            v = yc[(i + 1) * 8 + (j + 1)] - yc[(i + 1) * 8 + j]
              - yc[i * 8 + (j + 1)] + yc[i * 8 + j];
        }
        Ds[e] = v;
    }
    __syncthreads();

    // pass 1: strict column prefix
    for (int e = tid; e < 32 * DROW; e += 256) {
        int c = e / DROW, q = e - c * DROW;
        float v = 0.f;
        if (q < 49) {
            int i = q / 7, j = q - i * 7;
            const float* Dc = Ds + c * DROW;
            for (int ii = 0; ii < i; ++ii) v += Dc[ii * 7 + j];
        }
        Cs[e] = v;
    }
    __syncthreads();

    // pass 2: strict row prefix -> strict 2D prefix
    for (int e = tid; e < 32 * DROW; e += 256) {
        int c = e / DROW, q = e - c * DROW;
        float v = 0.f;
        if (q < 49) {
            int i = q / 7, j = q - i * 7;
            const float* Cc = Cs + c * DROW;
            for (int jj = 0; jj < j; ++jj) v += Cc[i * 7 + jj];
        }
        Ps[e] = v;
    }
    __syncthreads();

    // level-2: 2x2 register-blocked, vectorized LDS reads
    {
        const int bc1 = tid >> 4, bc2 = tid & 15;
        const float* P0 = Ps + bc1 * DROW;
        const float* P1 = Ps + (bc1 + 16) * DROW;
        const float* D0 = Ds + bc2 * DROW;
        const float* D1 = Ds + (bc2 + 16) * DROW;
        float a00 = 0.f, a01 = 0.f, a10 = 0.f, a11 = 0.f;
#pragma unroll
        for (int qb = 0; qb < DROW; qb += 4) {
            float4 p0 = *reinterpret_cast<const float4*>(P0 + qb);
            float4 p1 = *reinterpret_cast<const float4*>(P1 + qb);
            float4 d0 = *reinterpret_cast<const float4*>(D0 + qb);
            float4 d1 = *reinterpret_cast<const float4*>(D1 + qb);
            a00 += p0.x*d0.x + p0.y*d0.y + p0.z*d0.z + p0.w*d0.w;
            a01 += p0.x*d1.x + p0.y*d1.y + p0.z*d1.z + p0.w*d1.w;
            a10 += p1.x*d0.x + p1.y*d0.y + p1.z*d0.z + p1.w*d0.w;
            a11 += p1.x*d1.x + p1.y*d1.y + p1.z*d1.z + p1.w*d1.w;
        }
        float* so = sig + (size_t)b * F_PAD + 32;
        so[bc1 * 32 + bc2]               = a00;
        so[bc1 * 32 + (bc2 + 16)]        = a01;
        so[(bc1 + 16) * 32 + bc2]        = a10;
        so[(bc1 + 16) * 32 + (bc2 + 16)] = a11;
    }

    // level-1 sums + zero sig pad
    if (tid < 32) {
        const float4* Dr = reinterpret_cast<const float4*>(Ds + tid * DROW);
        float4 s4 = {0.f, 0.f, 0.f, 0.f};
#pragma unroll
        for (int j = 0; j < 13; ++j) {
            float4 v = Dr[j];
            s4.x += v.x; s4.y += v.y; s4.z += v.z; s4.w += v.w;
        }
        sig[(size_t)b * F_PAD + tid] = s4.x + s4.y + s4.z + s4.w;
    } else if (tid < 64) {
        sig[(size_t)b * F_PAD + F_SIG + (tid - 32)] = 0.f;
    }
}

// ---------- per-feature sum / sumsq over batch ----------
__global__ void k_stats(const float* __restrict__ sig, float* __restrict__ sums,
                        float* __restrict__ sqs) {
    int f = blockIdx.x * 256 + threadIdx.x;
    if (f >= F_SIG) return;
    int r0 = blockIdx.y * 32;
    float s = 0.f, q = 0.f;
    for (int r = r0; r < r0 + 32; ++r) {
        float v = sig[(size_t)r * F_PAD + f];
        s += v;
        q = fmaf(v, v, q);
    }
    atomicAdd(&sums[f], s);
    atomicAdd(&sqs[f], q);
}

// ---------- BN fold ----------
__global__ void k_ab(const float* __restrict__ sums, const float* __restrict__ sqs,
                     const float* __restrict__ gamma, const float* __restrict__ beta,
                     float* __restrict__ Av, float* __restrict__ Bv) {
    int i = blockIdx.x * 256 + threadIdx.x;
    if (i >= F_PAD) return;
    float a = 0.f, bb = 0.f;
    if (i < F_SIG) {
        float m   = sums[i] * (1.f / 2048.f);
        float var = sqs[i] * (1.f / 2048.f) - m * m;
        a  = gamma[i] / sqrtf(var + 1e-5f);
        bb = beta[i] - m * a;
    }
    Av[i] = a;
    Bv[i] = bb;
}

// ---------- t[o] = lin_b[o] + sum_i Bv[i]*lin_w[o,i] ----------
__global__ void k_t(const float* __restrict__ lw, const float* __restrict__ Bv,
                    const float* __restrict__ lb, float* __restrict__ tvec) {
    int o = blockIdx.x, tid = threadIdx.x;
    const float* lr = lw + (size_t)o * F_SIG;
    float s = 0.f;
    for (int i = tid; i < F_SIG; i += 256) s = fmaf(Bv[i], lr[i], s);
#pragma unroll
    for (int d = 32; d; d >>= 1) s += __shfl_xor(s, d);
    __shared__ float red[4];
    if ((tid & 63) == 0) red[tid >> 6] = s;
    __syncthreads();
    if (tid == 0) tvec[o] = lb[o] + red[0] + red[1] + red[2] + red[3];
}

// ---------- split-K partials: part[z][k][i] = sum_{o in chunk z} fcw[k,o]*lin_w[o,i] ----------
__launch_bounds__(256)
__global__ void k_wf(const float* __restrict__ fcw, const float* __restrict__ lw,
                     float* __restrict__ part) {
    const int k  = __builtin_amdgcn_readfirstlane(blockIdx.y * 4 + (threadIdx.x >> 6));
    const int z  = blockIdx.z;
    const int ib = blockIdx.x * 256 + (threadIdx.x & 63) * 4;
    if (ib >= F_SIG) return;
    const float* fr = fcw + (size_t)k * F_SIG;
    const int o0 = z * OCHUNK;
    float r0 = 0.f, r1 = 0.f, r2 = 0.f, r3 = 0.f;
    for (int o = o0; o < o0 + OCHUNK; ++o) {
        float s = fr[o];
        float4 v = *reinterpret_cast<const float4*>(lw + (size_t)o * F_SIG + ib);
        r0 = fmaf(s, v.x, r0);
        r1 = fmaf(s, v.y, r1);
        r2 = fmaf(s, v.z, r2);
        r3 = fmaf(s, v.w, r3);
    }
    float* dst = part + ((size_t)z * K_CLS + k) * F_SIG + ib;
    dst[0] = r0; dst[1] = r1; dst[2] = r2; dst[3] = r3;
}

// ---------- reduce partials, fold Av, emit WfT[i*128 + k] ----------
__launch_bounds__(64)
__global__ void k_wfred(const float* __restrict__ part, const float* __restrict__ Av,
                        float* __restrict__ WfT) {
    const int i = blockIdx.x * 64 + threadIdx.x;
    const int k = blockIdx.y;
    if (i >= F_SIG) return;
    float w = 0.f;
    if (k < K_CLS) {
        float s = 0.f;
#pragma unroll
        for (int z = 0; z < OSPLIT; ++z)
            s += part[((size_t)z * K_CLS + k) * F_SIG + i];
        w = Av[i] * s;
    }
    WfT[(size_t)i * K_PAD + k] = w;
}

// ---------- bf[k] = fc_b[k] + sum_o fc_w[k,o]*t[o] ----------
__global__ void k_bf(const float* __restrict__ fcw, const float* __restrict__ tvec,
                     const float* __restrict__ fcb, float* __restrict__ bf) {
    int k = blockIdx.x, tid = threadIdx.x;
    float s = 0.f;
    if (k < K_CLS) {
        const float* fr = fcw + (size_t)k * F_SIG;
        for (int o = tid; o < F_SIG; o += 256) s = fmaf(fr[o], tvec[o], s);
    }
#pragma unroll
    for (int d = 32; d; d >>= 1) s += __shfl_xor(s, d);
    __shared__ float red[4];
    if ((tid & 63) == 0) red[tid >> 6] = s;
    __syncthreads();
    if (tid == 0) {
        float tot = red[0] + red[1] + red[2] + red[3];
        bf[k] = (k < K_CLS) ? (tot + fcb[k]) : 0.f;
    }
}

// ---------- out[r,k] = sum_i sig[r,i]*WfT[i,k] + bf[k]; 8 rows/block, lanes along k ----------
__launch_bounds__(256)
__global__ void k_out(const float* __restrict__ sig, const float* __restrict__ WfT,
                      const float* __restrict__ bf, float* __restrict__ out) {
    __shared__ __align__(16) float sl[8 * F_SIG];
    const int tid = threadIdx.x;
    const int r0 = blockIdx.x * 8;
    // stage 8 rows of sig
    for (int e = tid; e < 8 * (F_SIG / 4); e += 256) {
        int row = e / (F_SIG / 4), c4 = e - row * (F_SIG / 4);
        float4 v = *reinterpret_cast<const float4*>(sig + (size_t)(r0 + row) * F_PAD + c4 * 4);
        *reinterpret_cast<float4*>(sl + row * F_SIG + c4 * 4) = v;
    }
    __syncthreads();

    const int rl = tid >> 5;          // 0..7
    const int kb = tid & 31;          // k = kb*4 + j
    const float4* W4 = reinterpret_cast<const float4*>(WfT);
    const float* srow = sl + rl * F_SIG;
    float4 acc = {0.f, 0.f, 0.f, 0.f};
    for (int i = 0; i < F_SIG; ++i) {
        float ss = srow[i];
        float4 w = W4[i * 32 + kb];
        acc.x = fmaf(ss, w.x, acc.x);
        acc.y = fmaf(ss, w.y, acc.y);
        acc.z = fmaf(ss, w.z, acc.z);
        acc.w = fmaf(ss, w.w, acc.w);
    }
    const int r = r0 + rl;
    const int k0 = kb * 4;
    float a[4] = {acc.x, acc.y, acc.z, acc.w};
#pragma unroll
    for (int j = 0; j < 4; ++j) {
        int k = k0 + j;
        if (k < K_CLS) out[(size_t)r * K_CLS + k] = a[j] + bf[k];
    }
}

extern "C" void kernel_launch(void* const* d_in, const int* in_sizes, int n_in,
                              void* d_out, int out_size, void* d_ws, size_t ws_size,
                              hipStream_t stream) {
    (void)in_sizes; (void)n_in; (void)out_size; (void)ws_size;
    const float* feats = (const float*)d_in[0];
    const float* convw = (const float*)d_in[1];
    const float* gamma = (const float*)d_in[2];
    const float* beta  = (const float*)d_in[3];
    const float* linw  = (const float*)d_in[4];
    const float* linb  = (const float*)d_in[5];
    const float* fcw   = (const float*)d_in[6];
    const float* fcb   = (const float*)d_in[7];
    float* out = (float*)d_out;

    float* ws   = (float*)d_ws;
    float* sig  = ws;                                   // 2048*1088
    float* sums = sig + (size_t)N_B * F_PAD;            // 1088
    float* sqs  = sums + F_PAD;                         // 1088
    float* Av   = sqs + F_PAD;                          // 1088
    float* Bv   = Av + F_PAD;                           // 1088
    float* tvec = Bv + F_PAD;                           // 1056
    float* part = tvec + F_SIG;                         // 8*100*1056
    float* WfT  = part + (size_t)OSPLIT * K_CLS * F_SIG;// 1056*128
    float* bfv  = WfT + (size_t)F_SIG * K_PAD;          // 128
    float* wT   = bfv + K_PAD;                          // 576*32

    k_wt<<<72, 256, 0, stream>>>(convw, wT);
    hipMemsetAsync(sums, 0, 2 * F_PAD * sizeof(float), stream);
    k_convsig<<<N_B, 256, 0, stream>>>(feats, wT, sig);
    k_stats<<<dim3(5, 64), 256, 0, stream>>>(sig, sums, sqs);
    k_ab<<<5, 256, 0, stream>>>(sums, sqs, gamma, beta, Av, Bv);
    k_t<<<F_SIG, 256, 0, stream>>>(linw, Bv, linb, tvec);
    k_wf<<<dim3(5, 25, OSPLIT), 256, 0, stream>>>(fcw, linw, part);
    k_wfred<<<dim3(17, K_PAD), 64, 0, stream>>>(part, Av, WfT);
    k_bf<<<K_PAD, 256, 0, stream>>>(fcw, tvec, fcb, bfv);
    k_out<<<N_B / 8, 256, 0, stream>>>(sig, WfT, bfv, out);
}

// Round 4
// 163.598 us; speedup vs baseline: 1.5705x; 1.1569x over previous
//
#include <hip/hip_runtime.h>

#define N_B   2048
#define F_SIG 1056
#define F_PAD 1088
#define K_CLS 100
#define K_PAD 128
#define DROW   52          // 49 real + 3 pad, 16B-aligned rows
#define OSPLIT  8
#define OCHUNK 132

typedef __attribute__((ext_vector_type(8))) short s8v;     // 8 bf16 in 4 VGPRs
typedef __attribute__((ext_vector_type(4))) float f4v;

__device__ __host__ __forceinline__ void split_bf16(float x, unsigned& h, unsigned& l) {
    unsigned u = __builtin_bit_cast(unsigned, x);
    unsigned hb = (u + 0x7FFFu + ((u >> 16) & 1u)) >> 16;
    float hf = __builtin_bit_cast(float, hb << 16);
    float r = x - hf;
    unsigned ur = __builtin_bit_cast(unsigned, r);
    unsigned lb = (ur + 0x7FFFu + ((ur >> 16) & 1u)) >> 16;
    h = hb & 0xFFFFu; l = lb & 0xFFFFu;
}

// ---------- prepack conv weights into MFMA A-fragments (hi/lo split) ----------
// frag f = ((tap*2+ch)*2+mt); element (lane,e): oc = mt*16+(lane&15),
// cin = ch*32+(lane>>4)*8+e, value = cw[oc][cin][tap]
__global__ void k_wt(const float* __restrict__ cw, unsigned short* __restrict__ Ahi,
                     unsigned short* __restrict__ Alo) {
    int t = blockIdx.x * 256 + threadIdx.x;
    if (t >= 36 * 512) return;
    int f = t >> 9, r = t & 511, lane = r >> 3, e = r & 7;
    int mt = f & 1, ch = (f >> 1) & 1, tap = f >> 2;
    int oc  = mt * 16 + (lane & 15);
    int cin = ch * 32 + (lane >> 4) * 8 + e;
    float v = cw[oc * 576 + cin * 9 + tap];
    unsigned h, l;
    split_bf16(v, h, l);
    Ahi[t] = (unsigned short)h;
    Alo[t] = (unsigned short)l;
}

// ---------- MFMA conv(64->32,3x3,pad1) + Zhang signature depth-2, one image/block ----------
__launch_bounds__(256, 4)
__global__ void k_convsig(const float* __restrict__ x,
                          const unsigned short* __restrict__ Ahi,
                          const unsigned short* __restrict__ Alo,
                          float* __restrict__ sig) {
    __shared__ __align__(16) unsigned xst[6600];     // [pad_pos 0..99][cin 0..63] stride 66, (hi<<16|lo)
    __shared__ __align__(16) float ysT[64 * 36];     // [pos 0..63][oc 0..31] stride 36
    float* Ds = (float*)xst;                         // phase-B aliases (xst dead)
    float* Ps = Ds + 1664;
    float* Cs = Ds + 3328;
    const int tid = threadIdx.x;
    const int b = blockIdx.x;

    // --- stage: zero-pad + split/pack feats into position-major LDS ---
    for (int e = tid; e < 6600; e += 256) xst[e] = 0u;
    __syncthreads();
    const float4* xb4 = reinterpret_cast<const float4*>(x + (size_t)b * 4096);
    for (int e = tid; e < 1024; e += 256) {
        float4 v = xb4[e];
        int cin = e >> 4, p = (e & 15) * 4;
        int ih = p >> 3, iw = p & 7;                   // iw in {0,4}
        int pp = (ih + 1) * 10 + (iw + 1);
        unsigned h, l;
        split_bf16(v.x, h, l); xst[(pp + 0) * 66 + cin] = (h << 16) | l;
        split_bf16(v.y, h, l); xst[(pp + 1) * 66 + cin] = (h << 16) | l;
        split_bf16(v.z, h, l); xst[(pp + 2) * 66 + cin] = (h << 16) | l;
        split_bf16(v.w, h, l); xst[(pp + 3) * 66 + cin] = (h << 16) | l;
    }
    __syncthreads();

    // --- MFMA conv: wave = one n-tile of 16 positions ---
    {
        const int wv = tid >> 6;
        const int lane = tid & 63;
        const int j = lane & 15, kg = lane >> 4;
        const int p2 = wv * 16 + j;
        const int oh = p2 >> 3, ow = p2 & 7;
        const char* xb = reinterpret_cast<const char*>(xst) + (oh * 10 + ow) * 264 + kg * 32;
        const char* Abh = reinterpret_cast<const char*>(Ahi) + lane * 16;
        const char* Abl = reinterpret_cast<const char*>(Alo) + lane * 16;
        f4v acc0 = {0.f, 0.f, 0.f, 0.f};
        f4v acc1 = {0.f, 0.f, 0.f, 0.f};
#pragma unroll
        for (int tap = 0; tap < 9; ++tap) {
            const int th = tap / 3, tw = tap % 3;
#pragma unroll
            for (int ch = 0; ch < 2; ++ch) {
                const int fb = ((tap * 2 + ch) * 2) * 1024;
                uint4 a0h = *reinterpret_cast<const uint4*>(Abh + fb);
                uint4 a0l = *reinterpret_cast<const uint4*>(Abl + fb);
                uint4 a1h = *reinterpret_cast<const uint4*>(Abh + fb + 1024);
                uint4 a1l = *reinterpret_cast<const uint4*>(Abl + fb + 1024);
                const int off = (th * 10 + tw) * 264 + ch * 128;
                uint4 w0 = *reinterpret_cast<const uint4*>(xb + off);
                uint4 w1 = *reinterpret_cast<const uint4*>(xb + off + 16);
                uint4 bh4, bl4;
                bh4.x = __builtin_amdgcn_perm(w0.y, w0.x, 0x07060302u);
                bl4.x = __builtin_amdgcn_perm(w0.y, w0.x, 0x05040100u);
                bh4.y = __builtin_amdgcn_perm(w0.w, w0.z, 0x07060302u);
                bl4.y = __builtin_amdgcn_perm(w0.w, w0.z, 0x05040100u);
                bh4.z = __builtin_amdgcn_perm(w1.y, w1.x, 0x07060302u);
                bl4.z = __builtin_amdgcn_perm(w1.y, w1.x, 0x05040100u);
                bh4.w = __builtin_amdgcn_perm(w1.w, w1.z, 0x07060302u);
                bl4.w = __builtin_amdgcn_perm(w1.w, w1.z, 0x05040100u);
                s8v Bh = __builtin_bit_cast(s8v, bh4);
                s8v Bl = __builtin_bit_cast(s8v, bl4);
                s8v A0h = __builtin_bit_cast(s8v, a0h);
                s8v A0l = __builtin_bit_cast(s8v, a0l);
                s8v A1h = __builtin_bit_cast(s8v, a1h);
                s8v A1l = __builtin_bit_cast(s8v, a1l);
                acc0 = __builtin_amdgcn_mfma_f32_16x16x32_bf16(A0h, Bh, acc0, 0, 0, 0);
                acc0 = __builtin_amdgcn_mfma_f32_16x16x32_bf16(A0h, Bl, acc0, 0, 0, 0);
                acc0 = __builtin_amdgcn_mfma_f32_16x16x32_bf16(A0l, Bh, acc0, 0, 0, 0);
                acc1 = __builtin_amdgcn_mfma_f32_16x16x32_bf16(A1h, Bh, acc1, 0, 0, 0);
                acc1 = __builtin_amdgcn_mfma_f32_16x16x32_bf16(A1h, Bl, acc1, 0, 0, 0);
                acc1 = __builtin_amdgcn_mfma_f32_16x16x32_bf16(A1l, Bh, acc1, 0, 0, 0);
            }
        }
        // C/D: col=lane&15 -> pos, row=(lane>>4)*4+reg -> oc
        *reinterpret_cast<f4v*>(ysT + p2 * 36 + kg * 4)      = acc0;
        *reinterpret_cast<f4v*>(ysT + p2 * 36 + 16 + kg * 4) = acc1;
    }
    __syncthreads();

    // --- double increments D[c][52] from ysT[pos][oc] ---
    for (int e = tid; e < 32 * DROW; e += 256) {
        int c = e / DROW, q = e - c * DROW;
        float v = 0.f;
        if (q < 49) {
            int i = q / 7, j = q - i * 7;
            v = ysT[((i + 1) * 8 + (j + 1)) * 36 + c] - ysT[((i + 1) * 8 + j) * 36 + c]
              - ysT[(i * 8 + (j + 1)) * 36 + c] + ysT[(i * 8 + j) * 36 + c];
        }
        Ds[e] = v;
    }
    __syncthreads();

    // pass 1: strict column prefix
    for (int e = tid; e < 32 * DROW; e += 256) {
        int c = e / DROW, q = e - c * DROW;
        float v = 0.f;
        if (q < 49) {
            int i = q / 7, j = q - i * 7;
            const float* Dc = Ds + c * DROW;
            for (int ii = 0; ii < i; ++ii) v += Dc[ii * 7 + j];
        }
        Cs[e] = v;
    }
    __syncthreads();

    // pass 2: strict row prefix -> strict 2D prefix
    for (int e = tid; e < 32 * DROW; e += 256) {
        int c = e / DROW, q = e - c * DROW;
        float v = 0.f;
        if (q < 49) {
            int i = q / 7, j = q - i * 7;
            const float* Cc = Cs + c * DROW;
            for (int jj = 0; jj < j; ++jj) v += Cc[i * 7 + jj];
        }
        Ps[e] = v;
    }
    __syncthreads();

    // level-2: 2x2 register-blocked, vectorized LDS reads
    {
        const int bc1 = tid >> 4, bc2 = tid & 15;
        const float* P0 = Ps + bc1 * DROW;
        const float* P1 = Ps + (bc1 + 16) * DROW;
        const float* D0 = Ds + bc2 * DROW;
        const float* D1 = Ds + (bc2 + 16) * DROW;
        float a00 = 0.f, a01 = 0.f, a10 = 0.f, a11 = 0.f;
#pragma unroll
        for (int qb = 0; qb < DROW; qb += 4) {
            float4 p0 = *reinterpret_cast<const float4*>(P0 + qb);
            float4 p1 = *reinterpret_cast<const float4*>(P1 + qb);
            float4 d0 = *reinterpret_cast<const float4*>(D0 + qb);
            float4 d1 = *reinterpret_cast<const float4*>(D1 + qb);
            a00 += p0.x*d0.x + p0.y*d0.y + p0.z*d0.z + p0.w*d0.w;
            a01 += p0.x*d1.x + p0.y*d1.y + p0.z*d1.z + p0.w*d1.w;
            a10 += p1.x*d0.x + p1.y*d0.y + p1.z*d0.z + p1.w*d0.w;
            a11 += p1.x*d1.x + p1.y*d1.y + p1.z*d1.z + p1.w*d1.w;
        }
        float* so = sig + (size_t)b * F_PAD + 32;
        so[bc1 * 32 + bc2]               = a00;
        so[bc1 * 32 + (bc2 + 16)]        = a01;
        so[(bc1 + 16) * 32 + bc2]        = a10;
        so[(bc1 + 16) * 32 + (bc2 + 16)] = a11;
    }

    // level-1 sums + zero sig pad
    if (tid < 32) {
        const float4* Dr = reinterpret_cast<const float4*>(Ds + tid * DROW);
        float4 s4 = {0.f, 0.f, 0.f, 0.f};
#pragma unroll
        for (int j = 0; j < 13; ++j) {
            float4 v = Dr[j];
            s4.x += v.x; s4.y += v.y; s4.z += v.z; s4.w += v.w;
        }
        sig[(size_t)b * F_PAD + tid] = s4.x + s4.y + s4.z + s4.w;
    } else if (tid < 64) {
        sig[(size_t)b * F_PAD + F_SIG + (tid - 32)] = 0.f;
    }
}

// ---------- per-feature sum / sumsq over batch ----------
__global__ void k_stats(const float* __restrict__ sig, float* __restrict__ sums,
                        float* __restrict__ sqs) {
    int f = blockIdx.x * 256 + threadIdx.x;
    if (f >= F_SIG) return;
    int r0 = blockIdx.y * 32;
    float s = 0.f, q = 0.f;
    for (int r = r0; r < r0 + 32; ++r) {
        float v = sig[(size_t)r * F_PAD + f];
        s += v;
        q = fmaf(v, v, q);
    }
    atomicAdd(&sums[f], s);
    atomicAdd(&sqs[f], q);
}

// ---------- BN fold ----------
__global__ void k_ab(const float* __restrict__ sums, const float* __restrict__ sqs,
                     const float* __restrict__ gamma, const float* __restrict__ beta,
                     float* __restrict__ Av, float* __restrict__ Bv) {
    int i = blockIdx.x * 256 + threadIdx.x;
    if (i >= F_PAD) return;
    float a = 0.f, bb = 0.f;
    if (i < F_SIG) {
        float m   = sums[i] * (1.f / 2048.f);
        float var = sqs[i] * (1.f / 2048.f) - m * m;
        a  = gamma[i] / sqrtf(var + 1e-5f);
        bb = beta[i] - m * a;
    }
    Av[i] = a;
    Bv[i] = bb;
}

// ---------- t[o] = lin_b[o] + sum_i Bv[i]*lin_w[o,i] ----------
__global__ void k_t(const float* __restrict__ lw, const float* __restrict__ Bv,
                    const float* __restrict__ lb, float* __restrict__ tvec) {
    int o = blockIdx.x, tid = threadIdx.x;
    const float* lr = lw + (size_t)o * F_SIG;
    float s = 0.f;
    for (int i = tid; i < F_SIG; i += 256) s = fmaf(Bv[i], lr[i], s);
#pragma unroll
    for (int d = 32; d; d >>= 1) s += __shfl_xor(s, d);
    __shared__ float red[4];
    if ((tid & 63) == 0) red[tid >> 6] = s;
    __syncthreads();
    if (tid == 0) tvec[o] = lb[o] + red[0] + red[1] + red[2] + red[3];
}

// ---------- split-K partials: part[z][k][i] = sum_{o in chunk z} fcw[k,o]*lin_w[o,i] ----------
__launch_bounds__(256)
__global__ void k_wf(const float* __restrict__ fcw, const float* __restrict__ lw,
                     float* __restrict__ part) {
    const int k  = __builtin_amdgcn_readfirstlane(blockIdx.y * 4 + (threadIdx.x >> 6));
    const int z  = blockIdx.z;
    const int ib = blockIdx.x * 256 + (threadIdx.x & 63) * 4;
    if (ib >= F_SIG) return;
    const float* fr = fcw + (size_t)k * F_SIG;
    const int o0 = z * OCHUNK;
    float r0 = 0.f, r1 = 0.f, r2 = 0.f, r3 = 0.f;
    for (int o = o0; o < o0 + OCHUNK; ++o) {
        float s = fr[o];
        float4 v = *reinterpret_cast<const float4*>(lw + (size_t)o * F_SIG + ib);
        r0 = fmaf(s, v.x, r0);
        r1 = fmaf(s, v.y, r1);
        r2 = fmaf(s, v.z, r2);
        r3 = fmaf(s, v.w, r3);
    }
    float* dst = part + ((size_t)z * K_CLS + k) * F_SIG + ib;
    dst[0] = r0; dst[1] = r1; dst[2] = r2; dst[3] = r3;
}

// ---------- reduce partials, fold Av, emit WfT[i*128 + k] ----------
__launch_bounds__(64)
__global__ void k_wfred(const float* __restrict__ part, const float* __restrict__ Av,
                        float* __restrict__ WfT) {
    const int i = blockIdx.x * 64 + threadIdx.x;
    const int k = blockIdx.y;
    if (i >= F_SIG) return;
    float w = 0.f;
    if (k < K_CLS) {
        float s = 0.f;
#pragma unroll
        for (int z = 0; z < OSPLIT; ++z)
            s += part[((size_t)z * K_CLS + k) * F_SIG + i];
        w = Av[i] * s;
    }
    WfT[(size_t)i * K_PAD + k] = w;
}

// ---------- bf[k] = fc_b[k] + sum_o fc_w[k,o]*t[o] ----------
__global__ void k_bf(const float* __restrict__ fcw, const float* __restrict__ tvec,
                     const float* __restrict__ fcb, float* __restrict__ bf) {
    int k = blockIdx.x, tid = threadIdx.x;
    float s = 0.f;
    if (k < K_CLS) {
        const float* fr = fcw + (size_t)k * F_SIG;
        for (int o = tid; o < F_SIG; o += 256) s = fmaf(fr[o], tvec[o], s);
    }
#pragma unroll
    for (int d = 32; d; d >>= 1) s += __shfl_xor(s, d);
    __shared__ float red[4];
    if ((tid & 63) == 0) red[tid >> 6] = s;
    __syncthreads();
    if (tid == 0) {
        float tot = red[0] + red[1] + red[2] + red[3];
        bf[k] = (k < K_CLS) ? (tot + fcb[k]) : 0.f;
    }
}

// ---------- out[r,k] = sum_i sig[r,i]*WfT[i,k] + bf[k]; 8 rows/block, lanes along k ----------
__launch_bounds__(256)
__global__ void k_out(const float* __restrict__ sig, const float* __restrict__ WfT,
                      const float* __restrict__ bf, float* __restrict__ out) {
    __shared__ __align__(16) float sl[8 * F_SIG];
    const int tid = threadIdx.x;
    const int r0 = blockIdx.x * 8;
    for (int e = tid; e < 8 * (F_SIG / 4); e += 256) {
        int row = e / (F_SIG / 4), c4 = e - row * (F_SIG / 4);
        float4 v = *reinterpret_cast<const float4*>(sig + (size_t)(r0 + row) * F_PAD + c4 * 4);
        *reinterpret_cast<float4*>(sl + row * F_SIG + c4 * 4) = v;
    }
    __syncthreads();

    const int rl = tid >> 5;
    const int kb = tid & 31;
    const float4* W4 = reinterpret_cast<const float4*>(WfT);
    const float* srow = sl + rl * F_SIG;
    float4 acc = {0.f, 0.f, 0.f, 0.f};
    for (int i = 0; i < F_SIG; ++i) {
        float ss = srow[i];
        float4 w = W4[i * 32 + kb];
        acc.x = fmaf(ss, w.x, acc.x);
        acc.y = fmaf(ss, w.y, acc.y);
        acc.z = fmaf(ss, w.z, acc.z);
        acc.w = fmaf(ss, w.w, acc.w);
    }
    const int r = r0 + rl;
    const int k0 = kb * 4;
    float a[4] = {acc.x, acc.y, acc.z, acc.w};
#pragma unroll
    for (int j = 0; j < 4; ++j) {
        int k = k0 + j;
        if (k < K_CLS) out[(size_t)r * K_CLS + k] = a[j] + bf[k];
    }
}

extern "C" void kernel_launch(void* const* d_in, const int* in_sizes, int n_in,
                              void* d_out, int out_size, void* d_ws, size_t ws_size,
                              hipStream_t stream) {
    (void)in_sizes; (void)n_in; (void)out_size; (void)ws_size;
    const float* feats = (const float*)d_in[0];
    const float* convw = (const float*)d_in[1];
    const float* gamma = (const float*)d_in[2];
    const float* beta  = (const float*)d_in[3];
    const float* linw  = (const float*)d_in[4];
    const float* linb  = (const float*)d_in[5];
    const float* fcw   = (const float*)d_in[6];
    const float* fcb   = (const float*)d_in[7];
    float* out = (float*)d_out;

    float* ws   = (float*)d_ws;
    float* sig  = ws;                                   // 2048*1088
    float* sums = sig + (size_t)N_B * F_PAD;            // 1088
    float* sqs  = sums + F_PAD;                         // 1088
    float* Av   = sqs + F_PAD;                          // 1088
    float* Bv   = Av + F_PAD;                           // 1088
    float* tvec = Bv + F_PAD;                           // 1056
    float* part = tvec + F_SIG;                         // 8*100*1056
    float* WfT  = part + (size_t)OSPLIT * K_CLS * F_SIG;// 1056*128
    float* bfv  = WfT + (size_t)F_SIG * K_PAD;          // 128
    unsigned short* Ahi = (unsigned short*)(bfv + K_PAD);   // 36*512 ushort
    unsigned short* Alo = Ahi + 36 * 512;

    k_wt<<<72, 256, 0, stream>>>(convw, Ahi, Alo);
    hipMemsetAsync(sums, 0, 2 * F_PAD * sizeof(float), stream);
    k_convsig<<<N_B, 256, 0, stream>>>(feats, Ahi, Alo, sig);
    k_stats<<<dim3(5, 64), 256, 0, stream>>>(sig, sums, sqs);
    k_ab<<<5, 256, 0, stream>>>(sums, sqs, gamma, beta, Av, Bv);
    k_t<<<F_SIG, 256, 0, stream>>>(linw, Bv, linb, tvec);
    k_wf<<<dim3(5, 25, OSPLIT), 256, 0, stream>>>(fcw, linw, part);
    k_wfred<<<dim3(17, K_PAD), 64, 0, stream>>>(part, Av, WfT);
    k_bf<<<K_PAD, 256, 0, stream>>>(fcw, tvec, fcb, bfv);
    k_out<<<N_B / 8, 256, 0, stream>>>(sig, WfT, bfv, out);
}

// Round 5
// 140.759 us; speedup vs baseline: 1.8253x; 1.1623x over previous
//
#include <hip/hip_runtime.h>

#define N_B   2048
#define F_SIG 1056
#define F_PAD 1088
#define K_CLS 100
#define K_PAD 128
#define KW_PAD 104         // k rows allocated in part[] (13 y-blocks x 8)
#define DROW   52          // 49 real + 3 pad, 16B-aligned rows
#define OSPLIT  8
#define OCHUNK 132
#define XW     72          // ushorts per padded-position row (16B-mult, bank-spread)

typedef __attribute__((ext_vector_type(8))) short s8v;     // 8 bf16 in 4 VGPRs
typedef __attribute__((ext_vector_type(4))) float f4v;

__device__ __host__ __forceinline__ void split_bf16(float x, unsigned& h, unsigned& l) {
    unsigned u = __builtin_bit_cast(unsigned, x);
    unsigned hb = (u + 0x7FFFu + ((u >> 16) & 1u)) >> 16;
    float hf = __builtin_bit_cast(float, hb << 16);
    float r = x - hf;
    unsigned ur = __builtin_bit_cast(unsigned, r);
    unsigned lb = (ur + 0x7FFFu + ((ur >> 16) & 1u)) >> 16;
    h = hb & 0xFFFFu; l = lb & 0xFFFFu;
}

// ---------- prepack conv weights into MFMA A-fragments (hi/lo split) ----------
// frag f = ((tap*2+ch)*2+mt); element (lane,e): oc = mt*16+(lane&15),
// cin = ch*32+(lane>>4)*8+e, value = cw[oc][cin][tap]   (layout verified R4)
__global__ void k_wt(const float* __restrict__ cw, unsigned short* __restrict__ Ahi,
                     unsigned short* __restrict__ Alo) {
    int t = blockIdx.x * 256 + threadIdx.x;
    if (t >= 36 * 512) return;
    int f = t >> 9, r = t & 511, lane = r >> 3, e = r & 7;
    int mt = f & 1, ch = (f >> 1) & 1, tap = f >> 2;
    int oc  = mt * 16 + (lane & 15);
    int cin = ch * 32 + (lane >> 4) * 8 + e;
    float v = cw[oc * 576 + cin * 9 + tap];
    unsigned h, l;
    split_bf16(v, h, l);
    Ahi[t] = (unsigned short)h;
    Alo[t] = (unsigned short)l;
}

// ---------- MFMA conv(64->32,3x3,pad1) + Zhang signature depth-2, one image/block ----------
__launch_bounds__(256, 4)
__global__ void k_convsig(const float* __restrict__ x,
                          const unsigned short* __restrict__ Ahi,
                          const unsigned short* __restrict__ Alo,
                          float* __restrict__ sig) {
    __shared__ __align__(16) unsigned short xhi[100 * XW];   // [pad_pos][cin] hi-plane
    __shared__ __align__(16) unsigned short xlo[100 * XW];   // lo-plane
    __shared__ __align__(16) float ysT[64 * 36];             // [pos][oc] stride 36
    float* Ds   = (float*)xhi;          // 32*52   (x planes dead after conv)
    float* Cs   = Ds + 1664;            // 32*52   in-place -> strict 2D prefix P
    float* colS = Cs + 1664;            // 32*8    column sums for level-1
    const int tid = threadIdx.x;
    const int b = blockIdx.x;

    // --- stage: zero planes, then split/scatter feats (position-major) ---
    {
        unsigned* zh = (unsigned*)xhi;
        unsigned* zl = (unsigned*)xlo;
        for (int e = tid; e < 100 * XW / 2; e += 256) { zh[e] = 0u; zl[e] = 0u; }
    }
    __syncthreads();
    const float4* xb4 = reinterpret_cast<const float4*>(x + (size_t)b * 4096);
    for (int e = tid; e < 1024; e += 256) {
        float4 v = xb4[e];
        int cin = e >> 4, p = (e & 15) * 4;
        int ih = p >> 3, iw = p & 7;                   // iw in {0,4}
        int pp = (ih + 1) * 10 + (iw + 1);
        unsigned h, l;
        split_bf16(v.x, h, l); xhi[(pp+0)*XW + cin] = (unsigned short)h; xlo[(pp+0)*XW + cin] = (unsigned short)l;
        split_bf16(v.y, h, l); xhi[(pp+1)*XW + cin] = (unsigned short)h; xlo[(pp+1)*XW + cin] = (unsigned short)l;
        split_bf16(v.z, h, l); xhi[(pp+2)*XW + cin] = (unsigned short)h; xlo[(pp+2)*XW + cin] = (unsigned short)l;
        split_bf16(v.w, h, l); xhi[(pp+3)*XW + cin] = (unsigned short)h; xlo[(pp+3)*XW + cin] = (unsigned short)l;
    }
    __syncthreads();

    // --- MFMA conv: wave = one n-tile of 16 positions, 32 oc ---
    {
        const int wv = tid >> 6;
        const int lane = tid & 63;
        const int j16 = lane & 15, kg = lane >> 4;
        const int p2 = wv * 16 + j16;
        const int oh = p2 >> 3, ow = p2 & 7;
        const unsigned short* Hb = xhi + (oh * 10 + ow) * XW + kg * 8;
        const unsigned short* Lb = xlo + (oh * 10 + ow) * XW + kg * 8;
        const uint4* AH = reinterpret_cast<const uint4*>(Ahi) + lane;  // frag f at +f*64
        const uint4* AL = reinterpret_cast<const uint4*>(Alo) + lane;
        f4v acc0 = {0.f, 0.f, 0.f, 0.f};
        f4v acc1 = {0.f, 0.f, 0.f, 0.f};
#pragma unroll
        for (int k = 0; k < 18; ++k) {
            const int tap = k >> 1, ch = k & 1;
            const int th = tap / 3, tw = tap % 3;          // fold at compile time
            const int xoff = (th * 10 + tw) * XW + ch * 32;
            const int f0 = (tap * 2 + ch) * 2;
            uint4 bh = *reinterpret_cast<const uint4*>(Hb + xoff);
            uint4 bl = *reinterpret_cast<const uint4*>(Lb + xoff);
            uint4 a0h = AH[f0 * 64], a0l = AL[f0 * 64];
            uint4 a1h = AH[f0 * 64 + 64], a1l = AL[f0 * 64 + 64];
            s8v Bh = __builtin_bit_cast(s8v, bh);
            s8v Bl = __builtin_bit_cast(s8v, bl);
            s8v A0h = __builtin_bit_cast(s8v, a0h);
            s8v A0l = __builtin_bit_cast(s8v, a0l);
            s8v A1h = __builtin_bit_cast(s8v, a1h);
            s8v A1l = __builtin_bit_cast(s8v, a1l);
            acc0 = __builtin_amdgcn_mfma_f32_16x16x32_bf16(A0h, Bh, acc0, 0, 0, 0);
            acc0 = __builtin_amdgcn_mfma_f32_16x16x32_bf16(A0h, Bl, acc0, 0, 0, 0);
            acc0 = __builtin_amdgcn_mfma_f32_16x16x32_bf16(A0l, Bh, acc0, 0, 0, 0);
            acc1 = __builtin_amdgcn_mfma_f32_16x16x32_bf16(A1h, Bh, acc1, 0, 0, 0);
            acc1 = __builtin_amdgcn_mfma_f32_16x16x32_bf16(A1h, Bl, acc1, 0, 0, 0);
            acc1 = __builtin_amdgcn_mfma_f32_16x16x32_bf16(A1l, Bh, acc1, 0, 0, 0);
        }
        // C/D: col=lane&15 -> pos, row=(lane>>4)*4+reg -> oc
        *reinterpret_cast<f4v*>(ysT + p2 * 36 + kg * 4)      = acc0;
        *reinterpret_cast<f4v*>(ysT + p2 * 36 + 16 + kg * 4) = acc1;
    }
    __syncthreads();

    // --- fused D + strict column scan; thread = (c, j) ---
    if (tid < 224) {
        const int c = tid / 7, j = tid - (tid / 7) * 7;
        float a  = ysT[j * 36 + c];            // ys[0][j]
        float bq = ysT[(j + 1) * 36 + c];      // ys[0][j+1]
        float run = 0.f;
        float* Dc = Ds + c * DROW;
        float* Cc = Cs + c * DROW;
#pragma unroll
        for (int i = 0; i < 7; ++i) {
            float a2 = ysT[((i + 1) * 8 + j) * 36 + c];
            float b2 = ysT[((i + 1) * 8 + j + 1) * 36 + c];
            float d = (b2 - a2) - (bq - a);
            Dc[i * 7 + j] = d;
            Cc[i * 7 + j] = run;               // strict prefix along i
            run += d;
            a = a2; bq = b2;
        }
        colS[c * 8 + j] = run;                 // full column sum (for level-1)
    } else {
        const int c = tid - 224;               // zero D row pads
        Ds[c * DROW + 49] = 0.f; Ds[c * DROW + 50] = 0.f; Ds[c * DROW + 51] = 0.f;
    }
    __syncthreads();

    // --- in-place strict row scan: Cs becomes strict 2D prefix P; thread = (c, i) ---
    if (tid < 224) {
        const int c = tid / 7, i = tid - (tid / 7) * 7;
        float* Cc = Cs + c * DROW + i * 7;
        float run = 0.f;
#pragma unroll
        for (int j = 0; j < 7; ++j) {
            float v = Cc[j];
            Cc[j] = run;
            run += v;
        }
    } else {
        const int c = tid - 224;               // zero P row pads
        Cs[c * DROW + 49] = 0.f; Cs[c * DROW + 50] = 0.f; Cs[c * DROW + 51] = 0.f;
    }
    __syncthreads();

    // --- level-2: 2x2 register-blocked, vectorized LDS reads (P = Cs) ---
    {
        const int bc1 = tid >> 4, bc2 = tid & 15;
        const float* P0 = Cs + bc1 * DROW;
        const float* P1 = Cs + (bc1 + 16) * DROW;
        const float* D0 = Ds + bc2 * DROW;
        const float* D1 = Ds + (bc2 + 16) * DROW;
        float a00 = 0.f, a01 = 0.f, a10 = 0.f, a11 = 0.f;
#pragma unroll
        for (int qb = 0; qb < DROW; qb += 4) {
            float4 p0 = *reinterpret_cast<const float4*>(P0 + qb);
            float4 p1 = *reinterpret_cast<const float4*>(P1 + qb);
            float4 d0 = *reinterpret_cast<const float4*>(D0 + qb);
            float4 d1 = *reinterpret_cast<const float4*>(D1 + qb);
            a00 += p0.x*d0.x + p0.y*d0.y + p0.z*d0.z + p0.w*d0.w;
            a01 += p0.x*d1.x + p0.y*d1.y + p0.z*d1.z + p0.w*d1.w;
            a10 += p1.x*d0.x + p1.y*d0.y + p1.z*d0.z + p1.w*d0.w;
            a11 += p1.x*d1.x + p1.y*d1.y + p1.z*d1.z + p1.w*d1.w;
        }
        float* so = sig + (size_t)b * F_PAD + 32;
        so[bc1 * 32 + bc2]               = a00;
        so[bc1 * 32 + (bc2 + 16)]        = a01;
        so[(bc1 + 16) * 32 + bc2]        = a10;
        so[(bc1 + 16) * 32 + (bc2 + 16)] = a11;
    }

    // --- level-1 from column sums + zero sig pad ---
    if (tid < 32) {
        const float* cr = colS + tid * 8;
        float s = cr[0] + cr[1] + cr[2] + cr[3] + cr[4] + cr[5] + cr[6];
        sig[(size_t)b * F_PAD + tid] = s;
    } else if (tid < 64) {
        sig[(size_t)b * F_PAD + F_SIG + (tid - 32)] = 0.f;
    }
}

// ---------- per-feature sum / sumsq over batch (128 rows per block) ----------
__global__ void k_stats(const float* __restrict__ sig, float* __restrict__ sums,
                        float* __restrict__ sqs) {
    int f = blockIdx.x * 256 + threadIdx.x;
    if (f >= F_SIG) return;
    int r0 = blockIdx.y * 128;
    float s = 0.f, q = 0.f;
    for (int r = r0; r < r0 + 128; ++r) {
        float v = sig[(size_t)r * F_PAD + f];
        s += v;
        q = fmaf(v, v, q);
    }
    atomicAdd(&sums[f], s);
    atomicAdd(&sqs[f], q);
}

// ---------- BN fold ----------
__global__ void k_ab(const float* __restrict__ sums, const float* __restrict__ sqs,
                     const float* __restrict__ gamma, const float* __restrict__ beta,
                     float* __restrict__ Av, float* __restrict__ Bv) {
    int i = blockIdx.x * 256 + threadIdx.x;
    if (i >= F_PAD) return;
    float a = 0.f, bb = 0.f;
    if (i < F_SIG) {
        float m   = sums[i] * (1.f / 2048.f);
        float var = sqs[i] * (1.f / 2048.f) - m * m;
        a  = gamma[i] / sqrtf(var + 1e-5f);
        bb = beta[i] - m * a;
    }
    Av[i] = a;
    Bv[i] = bb;
}

// ---------- t[o] = lin_b[o] + sum_i Bv[i]*lin_w[o,i] ----------
__global__ void k_t(const float* __restrict__ lw, const float* __restrict__ Bv,
                    const float* __restrict__ lb, float* __restrict__ tvec) {
    int o = blockIdx.x, tid = threadIdx.x;
    const float* lr = lw + (size_t)o * F_SIG;
    float s = 0.f;
    for (int i = tid; i < F_SIG; i += 256) s = fmaf(Bv[i], lr[i], s);
#pragma unroll
    for (int d = 32; d; d >>= 1) s += __shfl_xor(s, d);
    __shared__ float red[4];
    if ((tid & 63) == 0) red[tid >> 6] = s;
    __syncthreads();
    if (tid == 0) tvec[o] = lb[o] + red[0] + red[1] + red[2] + red[3];
}

// ---------- split-K partials: part[z][k][i] += fcw[k,o]*lin_w[o,i], 8 k per block ----------
__launch_bounds__(256)
__global__ void k_wf(const float* __restrict__ fcw, const float* __restrict__ lw,
                     float* __restrict__ part) {
    const int wv = threadIdx.x >> 6;
    const int k0 = blockIdx.y * 8 + wv * 2;         // this wave's two k rows
    const int z  = blockIdx.z;
    const int ib = blockIdx.x * 256 + (threadIdx.x & 63) * 4;
    if (ib >= F_SIG) return;
    const float* f0 = fcw + (size_t)min(k0,     K_CLS - 1) * F_SIG;
    const float* f1 = fcw + (size_t)min(k0 + 1, K_CLS - 1) * F_SIG;
    const int o0 = z * OCHUNK;
    float4 A0 = {0.f,0.f,0.f,0.f}, A1 = {0.f,0.f,0.f,0.f};
    for (int o = o0; o < o0 + OCHUNK; ++o) {
        float s0 = f0[o], s1 = f1[o];
        float4 v = *reinterpret_cast<const float4*>(lw + (size_t)o * F_SIG + ib);
        A0.x = fmaf(s0, v.x, A0.x); A0.y = fmaf(s0, v.y, A0.y);
        A0.z = fmaf(s0, v.z, A0.z); A0.w = fmaf(s0, v.w, A0.w);
        A1.x = fmaf(s1, v.x, A1.x); A1.y = fmaf(s1, v.y, A1.y);
        A1.z = fmaf(s1, v.z, A1.z); A1.w = fmaf(s1, v.w, A1.w);
    }
    *reinterpret_cast<float4*>(part + ((size_t)z * KW_PAD + k0) * F_SIG + ib)     = A0;
    *reinterpret_cast<float4*>(part + ((size_t)z * KW_PAD + k0 + 1) * F_SIG + ib) = A1;
}

// ---------- reduce partials, fold Av, emit WfT[i*128 + k] ----------
__launch_bounds__(64)
__global__ void k_wfred(const float* __restrict__ part, const float* __restrict__ Av,
                        float* __restrict__ WfT) {
    const int i = blockIdx.x * 64 + threadIdx.x;
    const int k = blockIdx.y;
    if (i >= F_SIG) return;
    float w = 0.f;
    if (k < K_CLS) {
        float s = 0.f;
#pragma unroll
        for (int z = 0; z < OSPLIT; ++z)
            s += part[((size_t)z * KW_PAD + k) * F_SIG + i];
        w = Av[i] * s;
    }
    WfT[(size_t)i * K_PAD + k] = w;
}

// ---------- bf[k] = fc_b[k] + sum_o fc_w[k,o]*t[o] ----------
__global__ void k_bf(const float* __restrict__ fcw, const float* __restrict__ tvec,
                     const float* __restrict__ fcb, float* __restrict__ bf) {
    int k = blockIdx.x, tid = threadIdx.x;
    float s = 0.f;
    if (k < K_CLS) {
        const float* fr = fcw + (size_t)k * F_SIG;
        for (int o = tid; o < F_SIG; o += 256) s = fmaf(fr[o], tvec[o], s);
    }
#pragma unroll
    for (int d = 32; d; d >>= 1) s += __shfl_xor(s, d);
    __shared__ float red[4];
    if ((tid & 63) == 0) red[tid >> 6] = s;
    __syncthreads();
    if (tid == 0) {
        float tot = red[0] + red[1] + red[2] + red[3];
        bf[k] = (k < K_CLS) ? (tot + fcb[k]) : 0.f;
    }
}

// ---------- out[r,k] = sum_i sig[r,i]*WfT[i,k] + bf[k]; 8 rows/block, lanes along k ----------
__launch_bounds__(256)
__global__ void k_out(const float* __restrict__ sig, const float* __restrict__ WfT,
                      const float* __restrict__ bf, float* __restrict__ out) {
    __shared__ __align__(16) float sl[8 * F_SIG];
    const int tid = threadIdx.x;
    const int r0 = blockIdx.x * 8;
    for (int e = tid; e < 8 * (F_SIG / 4); e += 256) {
        int row = e / (F_SIG / 4), c4 = e - row * (F_SIG / 4);
        float4 v = *reinterpret_cast<const float4*>(sig + (size_t)(r0 + row) * F_PAD + c4 * 4);
        *reinterpret_cast<float4*>(sl + row * F_SIG + c4 * 4) = v;
    }
    __syncthreads();

    const int rl = tid >> 5;
    const int kb = tid & 31;
    const float4* W4 = reinterpret_cast<const float4*>(WfT);
    const float* srow = sl + rl * F_SIG;
    float4 acc = {0.f, 0.f, 0.f, 0.f};
    for (int i = 0; i < F_SIG; ++i) {
        float ss = srow[i];
        float4 w = W4[i * 32 + kb];
        acc.x = fmaf(ss, w.x, acc.x);
        acc.y = fmaf(ss, w.y, acc.y);
        acc.z = fmaf(ss, w.z, acc.z);
        acc.w = fmaf(ss, w.w, acc.w);
    }
    const int r = r0 + rl;
    const int k0 = kb * 4;
    float a[4] = {acc.x, acc.y, acc.z, acc.w};
#pragma unroll
    for (int j = 0; j < 4; ++j) {
        int k = k0 + j;
        if (k < K_CLS) out[(size_t)r * K_CLS + k] = a[j] + bf[k];
    }
}

extern "C" void kernel_launch(void* const* d_in, const int* in_sizes, int n_in,
                              void* d_out, int out_size, void* d_ws, size_t ws_size,
                              hipStream_t stream) {
    (void)in_sizes; (void)n_in; (void)out_size; (void)ws_size;
    const float* feats = (const float*)d_in[0];
    const float* convw = (const float*)d_in[1];
    const float* gamma = (const float*)d_in[2];
    const float* beta  = (const float*)d_in[3];
    const float* linw  = (const float*)d_in[4];
    const float* linb  = (const float*)d_in[5];
    const float* fcw   = (const float*)d_in[6];
    const float* fcb   = (const float*)d_in[7];
    float* out = (float*)d_out;

    float* ws   = (float*)d_ws;
    float* sig  = ws;                                   // 2048*1088
    float* sums = sig + (size_t)N_B * F_PAD;            // 1088
    float* sqs  = sums + F_PAD;                         // 1088
    float* Av   = sqs + F_PAD;                          // 1088
    float* Bv   = Av + F_PAD;                           // 1088
    float* tvec = Bv + F_PAD;                           // 1056
    float* part = tvec + F_SIG;                         // 8*104*1056
    float* WfT  = part + (size_t)OSPLIT * KW_PAD * F_SIG;// 1056*128
    float* bfv  = WfT + (size_t)F_SIG * K_PAD;          // 128
    unsigned short* Ahi = (unsigned short*)(bfv + K_PAD);   // 36*512 ushort
    unsigned short* Alo = Ahi + 36 * 512;

    k_wt<<<72, 256, 0, stream>>>(convw, Ahi, Alo);
    hipMemsetAsync(sums, 0, 2 * F_PAD * sizeof(float), stream);
    k_convsig<<<N_B, 256, 0, stream>>>(feats, Ahi, Alo, sig);
    k_stats<<<dim3(5, 16), 256, 0, stream>>>(sig, sums, sqs);
    k_ab<<<5, 256, 0, stream>>>(sums, sqs, gamma, beta, Av, Bv);
    k_t<<<F_SIG, 256, 0, stream>>>(linw, Bv, linb, tvec);
    k_wf<<<dim3(5, 13, OSPLIT), 256, 0, stream>>>(fcw, linw, part);
    k_wfred<<<dim3(17, K_PAD), 64, 0, stream>>>(part, Av, WfT);
    k_bf<<<K_PAD, 256, 0, stream>>>(fcw, tvec, fcb, bfv);
    k_out<<<N_B / 8, 256, 0, stream>>>(sig, WfT, bfv, out);
}